// Round 12
// baseline (212.431 us; speedup 1.0000x reference)
//
#include <hip/hip_runtime.h>

// DRMM scoring kernel, round 12.
// Shapes: B=32, D=8, QL=16, DL=512, E=300, V=50000, 5 histogram bins.
// COALESCED GATHER: 4 consecutive lanes share one doc token; lane j loads
// chunks c=4m+j (byte offset 64m+16j) -> each group's 4 loads are one
// contiguous 64B run = ONE coalesced line transaction, each line fetched
// exactly once. R4's per-lane scatter issued 64 line-requests per wave-load
// and re-requested each line 4x (L1 thrash) -> ~38K L1 miss-handles per CU,
// the measured ~50us wall (R11 proved occupancy doesn't help -> shared
// per-CU gather throughput is the limit). This cuts line-requests ~4x.
// Each lane accumulates partial dots/norm over its quarter of E; shfl_xor
// (1,2) tree completes them (order change is safe: all 11 rounds matched a
// different-order reference bit-exactly -> no cos is near a bin edge).
// Histogram counts stay exact ints: per-lane u32 packed 5x6-bit (<=4/field),
// expanded to the u64 12-bit format for the exact wave reduce + LDS atomic.
// 512 thr/block, grid 256; depth-4 reload-in-place walk per lane (R4 idiom).

constexpr int Bn  = 32;
constexpr int Dn  = 8;
constexpr int QLn = 16;
constexpr int DLn = 512;
constexpr int En  = 300;

__global__ __launch_bounds__(512) void drmm_score(
    const int*   __restrict__ bq,    // [B,QL]
    const int*   __restrict__ bd,    // [B,D,DL]
    const float* __restrict__ emb,   // [V,E]
    const float* __restrict__ w_g,   // [E]
    const float* __restrict__ b_g,   // [1]
    const float* __restrict__ w1,    // [5]
    const float* __restrict__ b1,    // [1]
    const float* __restrict__ w2,    // [1]
    const float* __restrict__ b2,    // [1]
    const float* __restrict__ w_o,   // [1]
    const float* __restrict__ b_o,   // [1]
    float*       __restrict__ out)   // [B*D]
{
    __shared__ __attribute__((aligned(16))) float q_lds[QLn * En]; // 19200 B
    __shared__ float pn_s[QLn][17];
    __shared__ float pg_s[QLn][17];
    __shared__ float qn_s[QLn];
    __shared__ float gate_s[QLn];
    __shared__ float tw_s[QLn];
    __shared__ unsigned long long hist_s[QLn]; // 5 x 12-bit packed counters per q
    __shared__ float wsum_s[QLn];

    const int n   = blockIdx.x;   // 0..255  (b*8 + d)
    const int b   = n >> 3;
    const int tid = threadIdx.x;  // 0..511

    // ---- Phase 1: stage query embeddings into LDS (float4 granularity) ----
    for (int idx = tid; idx < QLn * (En / 4); idx += 512) {   // 1200 float4s
        const int  q   = idx / (En / 4);
        const int  c   = idx - q * (En / 4);
        const long tok = bq[b * QLn + q];
        *reinterpret_cast<float4*>(&q_lds[q * En + c * 4]) =
            *reinterpret_cast<const float4*>(emb + tok * (long)En + c * 4);
    }
    if (tid < QLn) hist_s[tid] = 0ull;
    __syncthreads();

    // ---- Phase 2: query norms + gate logits (16 threads per q) ----
    if (tid < 256) {
        const int q = tid >> 4, j = tid & 15;
        float pn = 0.f, pg = 0.f;
        for (int e = j; e < En; e += 16) {
            const float v = q_lds[q * En + e];
            pn = fmaf(v, v, pn);
            pg = fmaf(v, w_g[e], pg);
        }
        pn_s[q][j] = pn;
        pg_s[q][j] = pg;
    }
    __syncthreads();
    if (tid < QLn) {
        float sn = 0.f, sg = 0.f;
        for (int j = 0; j < 16; ++j) { sn += pn_s[tid][j]; sg += pg_s[tid][j]; }
        qn_s[tid]   = sqrtf(sn);
        gate_s[tid] = sg + b_g[0];
    }
    __syncthreads();
    if (tid == 0) {
        float m = gate_s[0];
        for (int q = 1; q < QLn; ++q) m = fmaxf(m, gate_s[q]);
        float ex[QLn];
        float s = 0.f;
        for (int q = 0; q < QLn; ++q) { ex[q] = expf(gate_s[q] - m); s += ex[q]; }
        for (int q = 0; q < QLn; ++q) tw_s[q] = ex[q] / s;
    }
    __syncthreads();

    // ---- Phase 3: cosine sims; 4 lanes per token, 128 tokens per pass ----
    const int j4 = (tid & 3) * 4;            // this lane's float offset in a line
    unsigned int cnt[QLn];
#pragma unroll
    for (int q = 0; q < QLn; ++q) cnt[q] = 0u;

    float acc[QLn];
    float nrm;

    // one 4-float chunk at runtime float-offset e_: partial norm + 16 q-FMAs
#define DRMM_CHUNK(dv, EV)                                                \
    do {                                                                  \
        const int e_ = (EV);                                              \
        nrm = fmaf((dv).x, (dv).x, nrm);                                  \
        nrm = fmaf((dv).y, (dv).y, nrm);                                  \
        nrm = fmaf((dv).z, (dv).z, nrm);                                  \
        nrm = fmaf((dv).w, (dv).w, nrm);                                  \
        _Pragma("unroll")                                                 \
        for (int q = 0; q < QLn; ++q) {                                   \
            const float4 qv =                                             \
                *reinterpret_cast<const float4*>(&q_lds[q * En + e_]);    \
            float a = acc[q];                                             \
            a = fmaf((dv).x, qv.x, a);                                    \
            a = fmaf((dv).y, qv.y, a);                                    \
            a = fmaf((dv).z, qv.z, a);                                    \
            a = fmaf((dv).w, qv.w, a);                                    \
            acc[q] = a;                                                   \
        }                                                                 \
    } while (0)

    // consume slot (line m), then reload the SAME slot from line m+4
#define DRMM_STEP_R(SA, MM)                                               \
    do {                                                                  \
        DRMM_CHUNK(SA, (MM) * 16 + j4);                                   \
        SA = *reinterpret_cast<const float4*>(pl + ((MM) + 4) * 16);      \
    } while (0)
#define DRMM_STEP_N(SA, MM) DRMM_CHUNK(SA, (MM) * 16 + j4)

#pragma unroll 1
    for (int pass = 0; pass < 4; ++pass) {
        const int  t   = pass * 128 + (tid >> 2);          // token slot
        const long tok = bd[n * DLn + t];
        const float* __restrict__ pl = emb + tok * (long)En + j4;

#pragma unroll
        for (int q = 0; q < QLn; ++q) acc[q] = 0.f;
        nrm = 0.f;

        // prologue: slots hold lines 0..3 (this lane's 16B of each)
        float4 s0 = *reinterpret_cast<const float4*>(pl +  0);
        float4 s1 = *reinterpret_cast<const float4*>(pl + 16);
        float4 s2 = *reinterpret_cast<const float4*>(pl + 32);
        float4 s3 = *reinterpret_cast<const float4*>(pl + 48);

#pragma unroll 1
        for (int k = 0; k < 3; ++k) {        // lines 0..11, reload 4..15
            const int m = k * 4;
            DRMM_STEP_R(s0, m + 0);
            DRMM_STEP_R(s1, m + 1);
            DRMM_STEP_R(s2, m + 2);
            DRMM_STEP_R(s3, m + 3);
        }
        DRMM_STEP_R(s0, 12);                 // reload line 16
        DRMM_STEP_R(s1, 13);                 // reload line 17
        DRMM_STEP_N(s2, 14);
        DRMM_STEP_N(s3, 15);
        DRMM_STEP_N(s0, 16);
        DRMM_STEP_N(s1, 17);
        // tail chunks 72..74 (e = 288 + j4), lanes j<3 only
        if (j4 < 12) {
            const float4 dt = *reinterpret_cast<const float4*>(pl + 288);
            DRMM_CHUNK(dt, 288 + j4);
        }

        // complete dots/norm across the 4-lane group: (p0+p1)+(p2+p3)
        nrm += __shfl_xor(nrm, 1, 64);
        nrm += __shfl_xor(nrm, 2, 64);
#pragma unroll
        for (int q = 0; q < QLn; ++q) {
            float a = acc[q];
            a += __shfl_xor(a, 1, 64);
            a += __shfl_xor(a, 2, 64);
            acc[q] = a;
        }

        const float dn = sqrtf(nrm);
        const bool  leader = (j4 == 0);
#pragma unroll
        for (int q = 0; q < QLn; ++q) {
            const float denom = fmaxf(qn_s[q] * dn, 1e-8f);
            const float c     = acc[q] / denom;
            // numpy.histogram semantics, edges [-1,-0.5,0,0.5,1,1]
            int bin = -1;
            if      (c >= -1.0f && c < -0.5f) bin = 0;
            else if (c >= -0.5f && c <  0.0f) bin = 1;
            else if (c >=  0.0f && c <  0.5f) bin = 2;
            else if (c >=  0.5f && c <  1.0f) bin = 3;
            else if (c ==  1.0f)              bin = 4;
            cnt[q] += (leader && bin >= 0) ? (1u << (6 * bin)) : 0u;
        }
    }
#undef DRMM_STEP_N
#undef DRMM_STEP_R
#undef DRMM_CHUNK

    // expand 6-bit fields to the u64 12-bit format, exact wave reduce, atomic
    const int lane = tid & 63;
#pragma unroll
    for (int q = 0; q < QLn; ++q) {
        unsigned long long v = 0ull;
#pragma unroll
        for (int bin = 0; bin < 5; ++bin)
            v |= (unsigned long long)((cnt[q] >> (6 * bin)) & 63u) << (12 * bin);
        for (int off = 32; off > 0; off >>= 1) v += __shfl_down(v, off, 64);
        if (lane == 0) atomicAdd(&hist_s[q], v);
    }
    __syncthreads();

    // ---- Phase 4: ffnn + gated sum -> score ----
    if (tid < QLn) {
        const unsigned long long h = hist_s[tid];
        float f = 0.f;
        f = fmaf((float)((h >>  0) & 0xFFFull), w1[0], f);
        f = fmaf((float)((h >> 12) & 0xFFFull), w1[1], f);
        f = fmaf((float)((h >> 24) & 0xFFFull), w1[2], f);
        f = fmaf((float)((h >> 36) & 0xFFFull), w1[3], f);
        f = fmaf((float)((h >> 48) & 0xFFFull), w1[4], f);
        f += b1[0];
        f = f * w2[0] + b2[0];
        wsum_s[tid] = f * tw_s[tid];
    }
    __syncthreads();
    if (tid == 0) {
        float s = 0.f;
        for (int q = 0; q < QLn; ++q) s += wsum_s[q];
        out[n] = s * w_o[0] + b_o[0];
    }
}

extern "C" void kernel_launch(void* const* d_in, const int* in_sizes, int n_in,
                              void* d_out, int out_size, void* d_ws, size_t ws_size,
                              hipStream_t stream) {
    const int*   bq  = (const int*)  d_in[0];  // batch_queries
    // d_in[1] query_len: unused by reference
    const int*   bd  = (const int*)  d_in[2];  // batch_docs
    // d_in[3] doc_len: unused by reference
    const float* emb = (const float*)d_in[4];
    const float* w_g = (const float*)d_in[5];
    const float* b_g = (const float*)d_in[6];
    const float* w1  = (const float*)d_in[7];
    const float* b1  = (const float*)d_in[8];
    const float* w2  = (const float*)d_in[9];
    const float* b2  = (const float*)d_in[10];
    const float* w_o = (const float*)d_in[11];
    const float* b_o = (const float*)d_in[12];

    drmm_score<<<Bn * Dn, 512, 0, stream>>>(
        bq, bd, emb, w_g, b_g, w1, b1, w2, b2, w_o, b_o, (float*)d_out);
}